// Round 3
// baseline (584.610 us; speedup 1.0000x reference)
//
#include <hip/hip_runtime.h>
#include <cstdint>

typedef unsigned short u16;
typedef float  f32x4 __attribute__((ext_vector_type(4)));
typedef short  s16x8 __attribute__((ext_vector_type(8)));

#define D_IN  4096
#define D_OUT 4096
#define RMOE  128
#define KAUG  4224   /* D_IN + RMOE */
#define NTOK  8192   /* B*S = 4*2048 */

__device__ __forceinline__ u16 f2bf(float f) {
    unsigned u = __builtin_bit_cast(unsigned, f);
    unsigned r = u + 0x7fffu + ((u >> 16) & 1u);   // RNE
    return (u16)(r >> 16);
}

__device__ __forceinline__ void gload16(const void* g, void* l) {
    __builtin_amdgcn_global_load_lds(
        (const __attribute__((address_space(1))) void*)g,
        (__attribute__((address_space(3))) void*)l, 16, 0, 0);
}

// ---------------------------------------------------------------------------
// Kernel 1: fp32 -> bf16 conversions into augmented layouts.
//   x[8192][4096]      -> Xaug[8192][4224] cols 0..4095
//   base_w[4096][4096] -> Waug[4096][4224] cols 0..4095
//   lora_B[4096][128]  -> Waug[4096][4224] cols 4096..4223
//   lora_A[128][4096]  -> A16 flat
// One thread = 8 elements (32B read, 16B write).
// ---------------------------------------------------------------------------
__global__ __launch_bounds__(256)
void convert_kernel(const float* __restrict__ x, const float* __restrict__ bw,
                    const float* __restrict__ lA, const float* __restrict__ lB,
                    u16* __restrict__ Xaug, u16* __restrict__ Waug,
                    u16* __restrict__ A16) {
    const long nx = (long)NTOK * D_IN / 8;    // 4,194,304
    const long nw = (long)D_OUT * D_IN / 8;   // 2,097,152
    const long nb = (long)D_OUT * RMOE / 8;   // 65,536
    long tid = (long)blockIdx.x * 256 + threadIdx.x;
    const float* src; u16* dst;
    if (tid < nx) {
        long e = tid * 8; long row = e >> 12; long col = e & 4095;
        src = x + e; dst = Xaug + row * KAUG + col;
    } else if (tid < nx + nw) {
        long e = (tid - nx) * 8; long row = e >> 12; long col = e & 4095;
        src = bw + e; dst = Waug + row * KAUG + col;
    } else if (tid < nx + nw + nb) {
        long e = (tid - nx - nw) * 8; long row = e >> 7; long col = e & 127;
        src = lB + e; dst = Waug + row * KAUG + D_IN + col;
    } else {
        long e = (tid - nx - nw - nb) * 8;
        src = lA + e; dst = A16 + e;
    }
    float4 a = ((const float4*)src)[0];
    float4 b = ((const float4*)src)[1];
    s16x8 o;
    o[0] = (short)f2bf(a.x); o[1] = (short)f2bf(a.y);
    o[2] = (short)f2bf(a.z); o[3] = (short)f2bf(a.w);
    o[4] = (short)f2bf(b.x); o[5] = (short)f2bf(b.y);
    o[6] = (short)f2bf(b.z); o[7] = (short)f2bf(b.w);
    *(s16x8*)dst = o;
}

// ---------------------------------------------------------------------------
// Kernel 2: router in fp32 (top-k selection must match the fp32 reference).
// One wave per token: 8 dot products of length 4096, butterfly reduce,
// top-2 (ties -> lower index, matching lax.top_k), softmax over the pair,
// store gate*scaling per expert (0 for unselected).
// ---------------------------------------------------------------------------
__global__ __launch_bounds__(256)
void router_kernel(const float* __restrict__ x, const float* __restrict__ rw,
                   const float* __restrict__ scal, float* __restrict__ gates) {
    int wave = threadIdx.x >> 6, lane = threadIdx.x & 63;
    int t = blockIdx.x * 4 + wave;
    const float4* xp = (const float4*)(x + (long)t * D_IN);
    float acc[8];
#pragma unroll
    for (int e = 0; e < 8; ++e) acc[e] = 0.f;
#pragma unroll 4
    for (int i = 0; i < 16; ++i) {
        float4 xv = xp[i * 64 + lane];
#pragma unroll
        for (int e = 0; e < 8; ++e) {
            float4 wv = ((const float4*)(rw + (long)e * D_IN))[i * 64 + lane];
            acc[e] += xv.x * wv.x + xv.y * wv.y + xv.z * wv.z + xv.w * wv.w;
        }
    }
#pragma unroll
    for (int e = 0; e < 8; ++e) {
#pragma unroll
        for (int off = 32; off > 0; off >>= 1)
            acc[e] += __shfl_xor(acc[e], off, 64);
    }
    if (lane == 0) {
        int i1 = 0; float v1 = acc[0];
#pragma unroll
        for (int e = 1; e < 8; ++e) if (acc[e] > v1) { v1 = acc[e]; i1 = e; }
        int i2 = -1; float v2 = -3.4e38f;
#pragma unroll
        for (int e = 0; e < 8; ++e) if (e != i1 && acc[e] > v2) { v2 = acc[e]; i2 = e; }
        float g1 = 1.f / (1.f + expf(v2 - v1));
        float g2 = 1.f - g1;
        float* gp = gates + (long)t * 8;
#pragma unroll
        for (int e = 0; e < 8; ++e)
            gp[e] = (e == i1) ? g1 * scal[e] : ((e == i2) ? g2 * scal[e] : 0.f);
    }
}

// ---------------------------------------------------------------------------
// Kernel 3: h_scaled = (x @ lora_A^T) * gate[group]*scaling, bf16, written into
// Xaug cols 4096..4223.  M=8192, N=128, K=4096.  BM=64, BN=64, BK=32,
// 4 waves (2x2), wave tile 32x32, acc 2x2 frags of 16x16x32 MFMA.
// ---------------------------------------------------------------------------
__global__ __launch_bounds__(256)
void lora_h_kernel(u16* __restrict__ Xaug, const u16* __restrict__ A16,
                   const float* __restrict__ gates) {
    __shared__ u16 sX[64 * 32];
    __shared__ u16 sW[64 * 32];
    int tid = threadIdx.x, wave = tid >> 6, lane = tid & 63;
    int bm = blockIdx.x >> 1, bn = blockIdx.x & 1;
    long m0 = (long)bm * 64; int n0 = bn * 64;
    int wr = wave >> 1, wc = wave & 1;
    int c = wave * 64 + lane, row = c >> 2, oct = c & 3;
    const u16* gx = Xaug + (m0 + row) * KAUG + oct * 8;
    const u16* gw = A16 + (long)(n0 + row) * D_IN + oct * 8;
    u16* lx = sX + wave * 512;   // wave-uniform LDS base (lane offset is HW-added)
    u16* lw = sW + wave * 512;
    int cl = lane & 15, kh = lane >> 4;
    int aoff[2], boff[2];
#pragma unroll
    for (int i = 0; i < 2; ++i) {
        aoff[i] = (wr * 32 + i * 16 + cl) * 32 + kh * 8;
        boff[i] = (wc * 32 + i * 16 + cl) * 32 + kh * 8;
    }
    f32x4 acc[2][2];
#pragma unroll
    for (int i = 0; i < 2; ++i)
#pragma unroll
        for (int j = 0; j < 2; ++j) acc[i][j] = (f32x4){0.f, 0.f, 0.f, 0.f};
    for (int kt = 0; kt < 128; ++kt) {
        __syncthreads();
        gload16(gx, lx); gload16(gw, lw);
        gx += 32; gw += 32;
        __syncthreads();
        s16x8 a[2], b[2];
#pragma unroll
        for (int i = 0; i < 2; ++i) {
            a[i] = *(const s16x8*)&sX[aoff[i]];
            b[i] = *(const s16x8*)&sW[boff[i]];
        }
#pragma unroll
        for (int mi = 0; mi < 2; ++mi)
#pragma unroll
            for (int ni = 0; ni < 2; ++ni)
                acc[mi][ni] = __builtin_amdgcn_mfma_f32_16x16x32_bf16(
                    a[mi], b[ni], acc[mi][ni], 0, 0, 0);
    }
#pragma unroll
    for (int ni = 0; ni < 2; ++ni) {
        int col = n0 + wc * 32 + ni * 16 + cl;   // rank index 0..127
        int g = col >> 4;                        // expert group (uniform per frag)
#pragma unroll
        for (int mi = 0; mi < 2; ++mi) {
#pragma unroll
            for (int r = 0; r < 4; ++r) {
                long tok = m0 + wr * 32 + mi * 16 + kh * 4 + r;
                float v = acc[mi][ni][r] * gates[tok * 8 + g];
                Xaug[tok * KAUG + D_IN + col] = f2bf(v);
            }
        }
    }
}

// ---------------------------------------------------------------------------
// Kernel 4: main GEMM  out[m][n] = sum_k Xaug[m][k]*Waug[n][k] + bias[n]
// M=8192, N=4096, K=4224.  m97 structure: 128x128 tile, BK=32, 4 waves (2x2),
// wave tile 64x64 (acc 4x4), global_load_lds width 16, 2 barriers per K-step.
// ---------------------------------------------------------------------------
__global__ __launch_bounds__(256)
void main_gemm(const u16* __restrict__ Xaug, const u16* __restrict__ Waug,
               const float* __restrict__ bias, float* __restrict__ out) {
    __shared__ u16 sA[128 * 32];
    __shared__ u16 sB[128 * 32];
    int tid = threadIdx.x, wave = tid >> 6, lane = tid & 63;
    int bm = blockIdx.x & 63, bn = blockIdx.x >> 6;
    long m0 = (long)bm * 128, n0 = (long)bn * 128;
    int wr = wave >> 1, wc = wave & 1;
    int c0 = wave * 128 + lane, c1 = c0 + 64;
    const u16* gA0 = Xaug + (m0 + (c0 >> 2)) * KAUG + (c0 & 3) * 8;
    const u16* gA1 = Xaug + (m0 + (c1 >> 2)) * KAUG + (c1 & 3) * 8;
    const u16* gB0 = Waug + (n0 + (c0 >> 2)) * KAUG + (c0 & 3) * 8;
    const u16* gB1 = Waug + (n0 + (c1 >> 2)) * KAUG + (c1 & 3) * 8;
    u16* lA0 = sA + wave * 1024;        // wave-uniform bases
    u16* lA1 = sA + wave * 1024 + 512;
    u16* lB0 = sB + wave * 1024;
    u16* lB1 = sB + wave * 1024 + 512;
    int cl = lane & 15, kh = lane >> 4;
    int aoff[4], boff[4];
#pragma unroll
    for (int i = 0; i < 4; ++i) {
        aoff[i] = (wr * 64 + i * 16 + cl) * 32 + kh * 8;
        boff[i] = (wc * 64 + i * 16 + cl) * 32 + kh * 8;
    }
    f32x4 acc[4][4];
#pragma unroll
    for (int i = 0; i < 4; ++i)
#pragma unroll
        for (int j = 0; j < 4; ++j) acc[i][j] = (f32x4){0.f, 0.f, 0.f, 0.f};
    for (int kt = 0; kt < 132; ++kt) {
        __syncthreads();
        gload16(gA0, lA0); gload16(gA1, lA1);
        gload16(gB0, lB0); gload16(gB1, lB1);
        gA0 += 32; gA1 += 32; gB0 += 32; gB1 += 32;
        __syncthreads();
        s16x8 a[4], b[4];
#pragma unroll
        for (int i = 0; i < 4; ++i) {
            a[i] = *(const s16x8*)&sA[aoff[i]];
            b[i] = *(const s16x8*)&sB[boff[i]];
        }
#pragma unroll
        for (int mi = 0; mi < 4; ++mi)
#pragma unroll
            for (int ni = 0; ni < 4; ++ni)
                acc[mi][ni] = __builtin_amdgcn_mfma_f32_16x16x32_bf16(
                    a[mi], b[ni], acc[mi][ni], 0, 0, 0);
    }
#pragma unroll
    for (int ni = 0; ni < 4; ++ni) {
        long col = n0 + wc * 64 + ni * 16 + cl;
        float bv = bias[col];
#pragma unroll
        for (int mi = 0; mi < 4; ++mi) {
            long row = m0 + wr * 64 + mi * 16 + kh * 4;
#pragma unroll
            for (int r = 0; r < 4; ++r)
                out[(row + r) * (long)D_OUT + col] = acc[mi][ni][r] + bv;
        }
    }
}

// ---------------------------------------------------------------------------
extern "C" void kernel_launch(void* const* d_in, const int* in_sizes, int n_in,
                              void* d_out, int out_size, void* d_ws, size_t ws_size,
                              hipStream_t stream) {
    const float* x  = (const float*)d_in[0];
    const float* bw = (const float*)d_in[1];
    const float* bb = (const float*)d_in[2];
    const float* lA = (const float*)d_in[3];
    const float* lB = (const float*)d_in[4];
    const float* rw = (const float*)d_in[5];
    const float* sc = (const float*)d_in[6];
    float* out = (float*)d_out;

    char* ws = (char*)d_ws;
    u16* Xaug  = (u16*)ws;                      // 8192*4224*2 = 69,206,016 B
    u16* Waug  = (u16*)(ws + 69206016);         // 4096*4224*2 = 34,603,008 B
    u16* A16   = (u16*)(ws + 103809024);        // 128*4096*2  =  1,048,576 B
    float* gates = (float*)(ws + 104857600);    // 8192*8*4    =    262,144 B

    convert_kernel<<<25088, 256, 0, stream>>>(x, bw, lA, lB, Xaug, Waug, A16);
    router_kernel<<<2048, 256, 0, stream>>>(x, rw, sc, gates);
    lora_h_kernel<<<256, 256, 0, stream>>>(Xaug, A16, gates);
    main_gemm<<<2048, 256, 0, stream>>>(Xaug, Waug, bb, out);
}

// Round 5
// 487.829 us; speedup vs baseline: 1.1984x; 1.1984x over previous
//
#include <hip/hip_runtime.h>
#include <cstdint>

typedef unsigned short u16;
typedef float  f32x4 __attribute__((ext_vector_type(4)));
typedef short  s16x8 __attribute__((ext_vector_type(8)));

#define D_IN  4096
#define D_OUT 4096
#define RMOE  128
#define KAUG  4224   /* D_IN + RMOE */
#define NTOK  8192   /* B*S = 4*2048 */

__device__ __forceinline__ u16 f2bf(float f) {
    unsigned u = __builtin_bit_cast(unsigned, f);
    unsigned r = u + 0x7fffu + ((u >> 16) & 1u);   // RNE
    return (u16)(r >> 16);
}

__device__ __forceinline__ void gload16(const void* g, void* l) {
    __builtin_amdgcn_global_load_lds(
        (const __attribute__((address_space(1))) void*)g,
        (__attribute__((address_space(3))) void*)l, 16, 0, 0);
}

// ---------------------------------------------------------------------------
// Kernel 1: fp32 -> bf16 conversions into augmented layouts. (unchanged)
// ---------------------------------------------------------------------------
__global__ __launch_bounds__(256)
void convert_kernel(const float* __restrict__ x, const float* __restrict__ bw,
                    const float* __restrict__ lA, const float* __restrict__ lB,
                    u16* __restrict__ Xaug, u16* __restrict__ Waug,
                    u16* __restrict__ A16) {
    const long nx = (long)NTOK * D_IN / 8;    // 4,194,304
    const long nw = (long)D_OUT * D_IN / 8;   // 2,097,152
    const long nb = (long)D_OUT * RMOE / 8;   // 65,536
    long tid = (long)blockIdx.x * 256 + threadIdx.x;
    const float* src; u16* dst;
    if (tid < nx) {
        long e = tid * 8; long row = e >> 12; long col = e & 4095;
        src = x + e; dst = Xaug + row * KAUG + col;
    } else if (tid < nx + nw) {
        long e = (tid - nx) * 8; long row = e >> 12; long col = e & 4095;
        src = bw + e; dst = Waug + row * KAUG + col;
    } else if (tid < nx + nw + nb) {
        long e = (tid - nx - nw) * 8; long row = e >> 7; long col = e & 127;
        src = lB + e; dst = Waug + row * KAUG + D_IN + col;
    } else {
        long e = (tid - nx - nw - nb) * 8;
        src = lA + e; dst = A16 + e;
    }
    float4 a = ((const float4*)src)[0];
    float4 b = ((const float4*)src)[1];
    s16x8 o;
    o[0] = (short)f2bf(a.x); o[1] = (short)f2bf(a.y);
    o[2] = (short)f2bf(a.z); o[3] = (short)f2bf(a.w);
    o[4] = (short)f2bf(b.x); o[5] = (short)f2bf(b.y);
    o[6] = (short)f2bf(b.z); o[7] = (short)f2bf(b.w);
    *(s16x8*)dst = o;
}

// ---------------------------------------------------------------------------
// Kernel 2: router in fp32. (unchanged)
// ---------------------------------------------------------------------------
__global__ __launch_bounds__(256)
void router_kernel(const float* __restrict__ x, const float* __restrict__ rw,
                   const float* __restrict__ scal, float* __restrict__ gates) {
    int wave = threadIdx.x >> 6, lane = threadIdx.x & 63;
    int t = blockIdx.x * 4 + wave;
    const float4* xp = (const float4*)(x + (long)t * D_IN);
    float acc[8];
#pragma unroll
    for (int e = 0; e < 8; ++e) acc[e] = 0.f;
#pragma unroll 4
    for (int i = 0; i < 16; ++i) {
        float4 xv = xp[i * 64 + lane];
#pragma unroll
        for (int e = 0; e < 8; ++e) {
            float4 wv = ((const float4*)(rw + (long)e * D_IN))[i * 64 + lane];
            acc[e] += xv.x * wv.x + xv.y * wv.y + xv.z * wv.z + xv.w * wv.w;
        }
    }
#pragma unroll
    for (int e = 0; e < 8; ++e) {
#pragma unroll
        for (int off = 32; off > 0; off >>= 1)
            acc[e] += __shfl_xor(acc[e], off, 64);
    }
    if (lane == 0) {
        int i1 = 0; float v1 = acc[0];
#pragma unroll
        for (int e = 1; e < 8; ++e) if (acc[e] > v1) { v1 = acc[e]; i1 = e; }
        int i2 = -1; float v2 = -3.4e38f;
#pragma unroll
        for (int e = 0; e < 8; ++e) if (e != i1 && acc[e] > v2) { v2 = acc[e]; i2 = e; }
        float g1 = 1.f / (1.f + expf(v2 - v1));
        float g2 = 1.f - g1;
        float* gp = gates + (long)t * 8;
#pragma unroll
        for (int e = 0; e < 8; ++e)
            gp[e] = (e == i1) ? g1 * scal[e] : ((e == i2) ? g2 * scal[e] : 0.f);
    }
}

// ---------------------------------------------------------------------------
// Kernel 3: h_scaled = (x @ lora_A^T) * gate, bf16 into Xaug cols 4096..4223.
// (unchanged)
// ---------------------------------------------------------------------------
__global__ __launch_bounds__(256)
void lora_h_kernel(u16* __restrict__ Xaug, const u16* __restrict__ A16,
                   const float* __restrict__ gates) {
    __shared__ u16 sX[64 * 32];
    __shared__ u16 sW[64 * 32];
    int tid = threadIdx.x, wave = tid >> 6, lane = tid & 63;
    int bm = blockIdx.x >> 1, bn = blockIdx.x & 1;
    long m0 = (long)bm * 64; int n0 = bn * 64;
    int wr = wave >> 1, wc = wave & 1;
    int c = wave * 64 + lane, row = c >> 2, oct = c & 3;
    const u16* gx = Xaug + (m0 + row) * KAUG + oct * 8;
    const u16* gw = A16 + (long)(n0 + row) * D_IN + oct * 8;
    u16* lx = sX + wave * 512;
    u16* lw = sW + wave * 512;
    int cl = lane & 15, kh = lane >> 4;
    int aoff[2], boff[2];
#pragma unroll
    for (int i = 0; i < 2; ++i) {
        aoff[i] = (wr * 32 + i * 16 + cl) * 32 + kh * 8;
        boff[i] = (wc * 32 + i * 16 + cl) * 32 + kh * 8;
    }
    f32x4 acc[2][2];
#pragma unroll
    for (int i = 0; i < 2; ++i)
#pragma unroll
        for (int j = 0; j < 2; ++j) acc[i][j] = (f32x4){0.f, 0.f, 0.f, 0.f};
    for (int kt = 0; kt < 128; ++kt) {
        __syncthreads();
        gload16(gx, lx); gload16(gw, lw);
        gx += 32; gw += 32;
        __syncthreads();
        s16x8 a[2], b[2];
#pragma unroll
        for (int i = 0; i < 2; ++i) {
            a[i] = *(const s16x8*)&sX[aoff[i]];
            b[i] = *(const s16x8*)&sW[boff[i]];
        }
#pragma unroll
        for (int mi = 0; mi < 2; ++mi)
#pragma unroll
            for (int ni = 0; ni < 2; ++ni)
                acc[mi][ni] = __builtin_amdgcn_mfma_f32_16x16x32_bf16(
                    a[mi], b[ni], acc[mi][ni], 0, 0, 0);
    }
#pragma unroll
    for (int ni = 0; ni < 2; ++ni) {
        int col = n0 + wc * 32 + ni * 16 + cl;
        int g = col >> 4;
#pragma unroll
        for (int mi = 0; mi < 2; ++mi) {
#pragma unroll
            for (int r = 0; r < 4; ++r) {
                long tok = m0 + wr * 32 + mi * 16 + kh * 4 + r;
                float v = acc[mi][ni][r] * gates[tok * 8 + g];
                Xaug[tok * KAUG + D_IN + col] = f2bf(v);
            }
        }
    }
}

// ---------------------------------------------------------------------------
// Kernel 4: main GEMM, 256x256 tile, BK=32, 8 waves (2Mx4N), 4-deep LDS
// pipeline with counted vmcnt (T3+T4) + setprio (T5) + XCD swizzle (T1)
// + T2 LDS swizzle (rule #21: linear gload_lds dest, inverse-swizzled
// GLOBAL source slot, same XOR on the ds_read offset).
//
// SYNC ORDER (race fix vs round 4): vmcnt(N) BEFORE s_barrier — each wave
// drains its own tile-t loads, THEN all waves sync => tile t globally
// visible. sched_barrier(0) after the barrier pins STAGE/ds_reads.
// STAGE(t+3) overwrites buf[(t-1)&3] only after barrier(t); all readers
// of that buffer completed before arriving at barrier(t).
// ---------------------------------------------------------------------------
__global__ __launch_bounds__(512, 2)
void main_gemm(const u16* __restrict__ Xaug, const u16* __restrict__ Waug,
               const float* __restrict__ bias, float* __restrict__ out) {
    __shared__ u16 lds[4 * 16384];     // 128 KiB
    const int tid = threadIdx.x;
    const int wave = tid >> 6, lane = tid & 63;
    const int cl = lane & 15, kh = lane >> 4;
    const int wr = wave >> 2, wc = wave & 3;

    // T1: bijective XCD swizzle (512 blocks, 512 % 8 == 0); each XCD gets a
    // contiguous 64-block chunk = full M column-strip of 2 N-blocks.
    int bid = blockIdx.x;
    int swz = (bid & 7) * 64 + (bid >> 3);
    long m0 = (long)(swz & 31) * 256;   // 32 M-blocks
    long n0 = (long)(swz >> 5) * 256;   // 16 N-blocks

    // staging: thread covers row rA (+128 for second half), 8-el slot.
    // T2: source slot XOR'd by ((row>>1)&3) — permutation within the row.
    const int rA = tid >> 2;
    const int sl = (((tid & 3) ^ ((tid >> 3) & 3))) * 8;
    const u16* gA0 = Xaug + (m0 + rA) * KAUG + sl;
    const u16* gA1 = Xaug + (m0 + 128 + rA) * KAUG + sl;
    const u16* gB0 = Waug + (n0 + rA) * KAUG + sl;
    const u16* gB1 = Waug + (n0 + 128 + rA) * KAUG + sl;
    const int wbase = wave * 512;       // wave-uniform LDS base (el)

    // T2 read side: slot kh ^ ((row>>1)&3); row ≡ cl (mod 16) in all frags.
    const int swk = (kh ^ ((cl >> 1) & 3)) * 8;
    const int aob = (wr * 128 + cl) * 32 + swk;
    const int bob = 8192 + (wc * 64 + cl) * 32 + swk;

    f32x4 acc[8][4];
#pragma unroll
    for (int m = 0; m < 8; ++m)
#pragma unroll
        for (int n = 0; n < 4; ++n) acc[m][n] = (f32x4){0.f, 0.f, 0.f, 0.f};

#define STAGE(t) do { u16* L = lds + ((t) & 3) * 16384 + wbase;              \
        gload16(gA0 + (t) * 32, L);                                          \
        gload16(gA1 + (t) * 32, L + 4096);                                   \
        gload16(gB0 + (t) * 32, L + 8192);                                   \
        gload16(gB1 + (t) * 32, L + 12288); } while (0)

    STAGE(0); STAGE(1); STAGE(2);       // 12 loads in flight

    for (int t = 0; t < 132; ++t) {
        if (t < 130)        asm volatile("s_waitcnt vmcnt(8)" ::: "memory");
        else if (t == 130)  asm volatile("s_waitcnt vmcnt(4)" ::: "memory");
        else                asm volatile("s_waitcnt vmcnt(0)" ::: "memory");
        __builtin_amdgcn_s_barrier();
        __builtin_amdgcn_sched_barrier(0);
        if (t + 3 < 132) STAGE(t + 3);

        const u16* Lb = lds + (t & 3) * 16384;
        s16x8 av[8], bv[4];
#pragma unroll
        for (int m = 0; m < 8; ++m) av[m] = *(const s16x8*)&Lb[aob + m * 512];
#pragma unroll
        for (int n = 0; n < 4; ++n) bv[n] = *(const s16x8*)&Lb[bob + n * 512];
        __builtin_amdgcn_s_setprio(1);
#pragma unroll
        for (int m = 0; m < 8; ++m)
#pragma unroll
            for (int n = 0; n < 4; ++n)
                acc[m][n] = __builtin_amdgcn_mfma_f32_16x16x32_bf16(
                    av[m], bv[n], acc[m][n], 0, 0, 0);
        __builtin_amdgcn_s_setprio(0);
    }
#undef STAGE

#pragma unroll
    for (int n = 0; n < 4; ++n) {
        long col = n0 + wc * 64 + n * 16 + cl;
        float bvv = bias[col];
#pragma unroll
        for (int m = 0; m < 8; ++m) {
            long row = m0 + wr * 128 + m * 16 + kh * 4;
#pragma unroll
            for (int r = 0; r < 4; ++r)
                out[(row + r) * (long)D_OUT + col] = acc[m][n][r] + bvv;
        }
    }
}

// ---------------------------------------------------------------------------
extern "C" void kernel_launch(void* const* d_in, const int* in_sizes, int n_in,
                              void* d_out, int out_size, void* d_ws, size_t ws_size,
                              hipStream_t stream) {
    const float* x  = (const float*)d_in[0];
    const float* bw = (const float*)d_in[1];
    const float* bb = (const float*)d_in[2];
    const float* lA = (const float*)d_in[3];
    const float* lB = (const float*)d_in[4];
    const float* rw = (const float*)d_in[5];
    const float* sc = (const float*)d_in[6];
    float* out = (float*)d_out;

    char* ws = (char*)d_ws;
    u16* Xaug  = (u16*)ws;                      // 8192*4224*2 = 69,206,016 B
    u16* Waug  = (u16*)(ws + 69206016);         // 4096*4224*2 = 34,603,008 B
    u16* A16   = (u16*)(ws + 103809024);        // 128*4096*2  =  1,048,576 B
    float* gates = (float*)(ws + 104857600);    // 8192*8*4    =    262,144 B

    convert_kernel<<<25088, 256, 0, stream>>>(x, bw, lA, lB, Xaug, Waug, A16);
    router_kernel<<<2048, 256, 0, stream>>>(x, rw, sc, gates);
    lora_h_kernel<<<256, 256, 0, stream>>>(Xaug, A16, gates);
    main_gemm<<<512, 512, 0, stream>>>(Xaug, Waug, bb, out);
}

// Round 6
// 477.306 us; speedup vs baseline: 1.2248x; 1.0220x over previous
//
#include <hip/hip_runtime.h>
#include <cstdint>

typedef unsigned short u16;
typedef float  f32x4 __attribute__((ext_vector_type(4)));
typedef short  s16x8 __attribute__((ext_vector_type(8)));

#define D_IN  4096
#define D_OUT 4096
#define RMOE  128
#define KAUG  4224   /* D_IN + RMOE */
#define NTOK  8192   /* B*S = 4*2048 */

__device__ __forceinline__ u16 f2bf(float f) {
    unsigned u = __builtin_bit_cast(unsigned, f);
    unsigned r = u + 0x7fffu + ((u >> 16) & 1u);   // RNE
    return (u16)(r >> 16);
}

__device__ __forceinline__ void gload16(const void* g, void* l) {
    __builtin_amdgcn_global_load_lds(
        (const __attribute__((address_space(1))) void*)g,
        (__attribute__((address_space(3))) void*)l, 16, 0, 0);
}

// ---------------------------------------------------------------------------
// Kernel 1: fp32 -> bf16 conversions into augmented layouts. (unchanged)
// ---------------------------------------------------------------------------
__global__ __launch_bounds__(256)
void convert_kernel(const float* __restrict__ x, const float* __restrict__ bw,
                    const float* __restrict__ lA, const float* __restrict__ lB,
                    u16* __restrict__ Xaug, u16* __restrict__ Waug,
                    u16* __restrict__ A16) {
    const long nx = (long)NTOK * D_IN / 8;    // 4,194,304
    const long nw = (long)D_OUT * D_IN / 8;   // 2,097,152
    const long nb = (long)D_OUT * RMOE / 8;   // 65,536
    long tid = (long)blockIdx.x * 256 + threadIdx.x;
    const float* src; u16* dst;
    if (tid < nx) {
        long e = tid * 8; long row = e >> 12; long col = e & 4095;
        src = x + e; dst = Xaug + row * KAUG + col;
    } else if (tid < nx + nw) {
        long e = (tid - nx) * 8; long row = e >> 12; long col = e & 4095;
        src = bw + e; dst = Waug + row * KAUG + col;
    } else if (tid < nx + nw + nb) {
        long e = (tid - nx - nw) * 8; long row = e >> 7; long col = e & 127;
        src = lB + e; dst = Waug + row * KAUG + D_IN + col;
    } else {
        long e = (tid - nx - nw - nb) * 8;
        src = lA + e; dst = A16 + e;
    }
    float4 a = ((const float4*)src)[0];
    float4 b = ((const float4*)src)[1];
    s16x8 o;
    o[0] = (short)f2bf(a.x); o[1] = (short)f2bf(a.y);
    o[2] = (short)f2bf(a.z); o[3] = (short)f2bf(a.w);
    o[4] = (short)f2bf(b.x); o[5] = (short)f2bf(b.y);
    o[6] = (short)f2bf(b.z); o[7] = (short)f2bf(b.w);
    *(s16x8*)dst = o;
}

// ---------------------------------------------------------------------------
// Kernel 2: router in fp32. (unchanged)
// ---------------------------------------------------------------------------
__global__ __launch_bounds__(256)
void router_kernel(const float* __restrict__ x, const float* __restrict__ rw,
                   const float* __restrict__ scal, float* __restrict__ gates) {
    int wave = threadIdx.x >> 6, lane = threadIdx.x & 63;
    int t = blockIdx.x * 4 + wave;
    const float4* xp = (const float4*)(x + (long)t * D_IN);
    float acc[8];
#pragma unroll
    for (int e = 0; e < 8; ++e) acc[e] = 0.f;
#pragma unroll 4
    for (int i = 0; i < 16; ++i) {
        float4 xv = xp[i * 64 + lane];
#pragma unroll
        for (int e = 0; e < 8; ++e) {
            float4 wv = ((const float4*)(rw + (long)e * D_IN))[i * 64 + lane];
            acc[e] += xv.x * wv.x + xv.y * wv.y + xv.z * wv.z + xv.w * wv.w;
        }
    }
#pragma unroll
    for (int e = 0; e < 8; ++e) {
#pragma unroll
        for (int off = 32; off > 0; off >>= 1)
            acc[e] += __shfl_xor(acc[e], off, 64);
    }
    if (lane == 0) {
        int i1 = 0; float v1 = acc[0];
#pragma unroll
        for (int e = 1; e < 8; ++e) if (acc[e] > v1) { v1 = acc[e]; i1 = e; }
        int i2 = -1; float v2 = -3.4e38f;
#pragma unroll
        for (int e = 0; e < 8; ++e) if (e != i1 && acc[e] > v2) { v2 = acc[e]; i2 = e; }
        float g1 = 1.f / (1.f + expf(v2 - v1));
        float g2 = 1.f - g1;
        float* gp = gates + (long)t * 8;
#pragma unroll
        for (int e = 0; e < 8; ++e)
            gp[e] = (e == i1) ? g1 * scal[e] : ((e == i2) ? g2 * scal[e] : 0.f);
    }
}

// ---------------------------------------------------------------------------
// Kernel 3: h_scaled = (x @ lora_A^T) * gate, bf16 into Xaug cols 4096..4223.
// (unchanged)
// ---------------------------------------------------------------------------
__global__ __launch_bounds__(256)
void lora_h_kernel(u16* __restrict__ Xaug, const u16* __restrict__ A16,
                   const float* __restrict__ gates) {
    __shared__ u16 sX[64 * 32];
    __shared__ u16 sW[64 * 32];
    int tid = threadIdx.x, wave = tid >> 6, lane = tid & 63;
    int bm = blockIdx.x >> 1, bn = blockIdx.x & 1;
    long m0 = (long)bm * 64; int n0 = bn * 64;
    int wr = wave >> 1, wc = wave & 1;
    int c = wave * 64 + lane, row = c >> 2, oct = c & 3;
    const u16* gx = Xaug + (m0 + row) * KAUG + oct * 8;
    const u16* gw = A16 + (long)(n0 + row) * D_IN + oct * 8;
    u16* lx = sX + wave * 512;
    u16* lw = sW + wave * 512;
    int cl = lane & 15, kh = lane >> 4;
    int aoff[2], boff[2];
#pragma unroll
    for (int i = 0; i < 2; ++i) {
        aoff[i] = (wr * 32 + i * 16 + cl) * 32 + kh * 8;
        boff[i] = (wc * 32 + i * 16 + cl) * 32 + kh * 8;
    }
    f32x4 acc[2][2];
#pragma unroll
    for (int i = 0; i < 2; ++i)
#pragma unroll
        for (int j = 0; j < 2; ++j) acc[i][j] = (f32x4){0.f, 0.f, 0.f, 0.f};
    for (int kt = 0; kt < 128; ++kt) {
        __syncthreads();
        gload16(gx, lx); gload16(gw, lw);
        gx += 32; gw += 32;
        __syncthreads();
        s16x8 a[2], b[2];
#pragma unroll
        for (int i = 0; i < 2; ++i) {
            a[i] = *(const s16x8*)&sX[aoff[i]];
            b[i] = *(const s16x8*)&sW[boff[i]];
        }
#pragma unroll
        for (int mi = 0; mi < 2; ++mi)
#pragma unroll
            for (int ni = 0; ni < 2; ++ni)
                acc[mi][ni] = __builtin_amdgcn_mfma_f32_16x16x32_bf16(
                    a[mi], b[ni], acc[mi][ni], 0, 0, 0);
    }
#pragma unroll
    for (int ni = 0; ni < 2; ++ni) {
        int col = n0 + wc * 32 + ni * 16 + cl;
        int g = col >> 4;
#pragma unroll
        for (int mi = 0; mi < 2; ++mi) {
#pragma unroll
            for (int r = 0; r < 4; ++r) {
                long tok = m0 + wr * 32 + mi * 16 + kh * 4 + r;
                float v = acc[mi][ni][r] * gates[tok * 8 + g];
                Xaug[tok * KAUG + D_IN + col] = f2bf(v);
            }
        }
    }
}

// ---------------------------------------------------------------------------
// Kernel 4: main GEMM, 256x256 tile, BK=32, 8 waves (2Mx4N), 4-deep LDS
// pipeline, counted vmcnt (T4) + XCD swizzle (T1) + T2 LDS swizzle.
//
// ROUND-5 CHANGE: 2-phase K-step (T3). Each tile's body is split into two
// {ds_read || stage || lgkmcnt(0) || setprio MFMA-16} phases separated by a
// mid-tile s_barrier — creates per-phase wave role diversity (T5 pays) and
// interleaves VMEM issue with MFMA.
//
// Sync skeleton (validated round 5): vmcnt(N) BEFORE s_barrier; STAGE(t+3)
// writes buf[(t-1)&3] whose readers all completed before barrier(t). The
// mid-tile barrier adds no data hazard: each wave's LDS reads of tile t are
// lgkmcnt(0)-drained before its MFMA cluster, hence complete before it
// reaches any later barrier; stages after the mid-barrier still target the
// old (freed) buffer. Per-tile 4-load issue invariant preserved -> the
// vmcnt(8)/4/0 ladder is unchanged.
// ---------------------------------------------------------------------------
__global__ __launch_bounds__(512, 2)
void main_gemm(const u16* __restrict__ Xaug, const u16* __restrict__ Waug,
               const float* __restrict__ bias, float* __restrict__ out) {
    __shared__ u16 lds[4 * 16384];     // 128 KiB
    const int tid = threadIdx.x;
    const int wave = tid >> 6, lane = tid & 63;
    const int cl = lane & 15, kh = lane >> 4;
    const int wr = wave >> 2, wc = wave & 3;

    // T1: bijective XCD swizzle (512 blocks, 512 % 8 == 0)
    int bid = blockIdx.x;
    int swz = (bid & 7) * 64 + (bid >> 3);
    long m0 = (long)(swz & 31) * 256;   // 32 M-blocks
    long n0 = (long)(swz >> 5) * 256;   // 16 N-blocks

    // staging: thread covers row rA (+128 for second half), 8-el slot.
    // T2: source slot XOR'd by ((row>>1)&3) — permutation within the row.
    const int rA = tid >> 2;
    const int sl = (((tid & 3) ^ ((tid >> 3) & 3))) * 8;
    const u16* gA0 = Xaug + (m0 + rA) * KAUG + sl;
    const u16* gA1 = Xaug + (m0 + 128 + rA) * KAUG + sl;
    const u16* gB0 = Waug + (n0 + rA) * KAUG + sl;
    const u16* gB1 = Waug + (n0 + 128 + rA) * KAUG + sl;
    const int wbase = wave * 512;       // wave-uniform LDS base (el)

    // T2 read side: slot kh ^ ((row>>1)&3); row ≡ cl (mod 16) in all frags.
    const int swk = (kh ^ ((cl >> 1) & 3)) * 8;
    const int aob = (wr * 128 + cl) * 32 + swk;
    const int bob = 8192 + (wc * 64 + cl) * 32 + swk;

    f32x4 acc[8][4];
#pragma unroll
    for (int m = 0; m < 8; ++m)
#pragma unroll
        for (int n = 0; n < 4; ++n) acc[m][n] = (f32x4){0.f, 0.f, 0.f, 0.f};

#define STAGE_A(t) do { u16* L = lds + ((t) & 3) * 16384 + wbase;            \
        gload16(gA0 + (t) * 32, L);                                          \
        gload16(gA1 + (t) * 32, L + 4096); } while (0)
#define STAGE_B(t) do { u16* L = lds + ((t) & 3) * 16384 + wbase;            \
        gload16(gB0 + (t) * 32, L + 8192);                                   \
        gload16(gB1 + (t) * 32, L + 12288); } while (0)

    STAGE_A(0); STAGE_B(0); STAGE_A(1); STAGE_B(1); STAGE_A(2); STAGE_B(2);

    for (int t = 0; t < 132; ++t) {
        if (t < 130)        asm volatile("s_waitcnt vmcnt(8)" ::: "memory");
        else if (t == 130)  asm volatile("s_waitcnt vmcnt(4)" ::: "memory");
        else                asm volatile("s_waitcnt vmcnt(0)" ::: "memory");
        __builtin_amdgcn_s_barrier();
        __builtin_amdgcn_sched_barrier(0);

        const u16* Lb = lds + (t & 3) * 16384;
        s16x8 av[8], bv[4];
        // ---- phase 0: read A0-3 + all B, stage A-half of t+3, MFMA m0-3
#pragma unroll
        for (int m = 0; m < 4; ++m) av[m] = *(const s16x8*)&Lb[aob + m * 512];
#pragma unroll
        for (int n = 0; n < 4; ++n) bv[n] = *(const s16x8*)&Lb[bob + n * 512];
        if (t + 3 < 132) STAGE_A(t + 3);
        asm volatile("s_waitcnt lgkmcnt(0)" ::: "memory");
        __builtin_amdgcn_sched_barrier(0);
        __builtin_amdgcn_s_setprio(1);
#pragma unroll
        for (int m = 0; m < 4; ++m)
#pragma unroll
            for (int n = 0; n < 4; ++n)
                acc[m][n] = __builtin_amdgcn_mfma_f32_16x16x32_bf16(
                    av[m], bv[n], acc[m][n], 0, 0, 0);
        __builtin_amdgcn_s_setprio(0);
        __builtin_amdgcn_s_barrier();       // mid-tile phase barrier
        // ---- phase 1: read A4-7, stage B-half of t+3, MFMA m4-7
#pragma unroll
        for (int m = 4; m < 8; ++m) av[m] = *(const s16x8*)&Lb[aob + m * 512];
        if (t + 3 < 132) STAGE_B(t + 3);
        asm volatile("s_waitcnt lgkmcnt(0)" ::: "memory");
        __builtin_amdgcn_sched_barrier(0);
        __builtin_amdgcn_s_setprio(1);
#pragma unroll
        for (int m = 4; m < 8; ++m)
#pragma unroll
            for (int n = 0; n < 4; ++n)
                acc[m][n] = __builtin_amdgcn_mfma_f32_16x16x32_bf16(
                    av[m], bv[n], acc[m][n], 0, 0, 0);
        __builtin_amdgcn_s_setprio(0);
    }
#undef STAGE_A
#undef STAGE_B

#pragma unroll
    for (int n = 0; n < 4; ++n) {
        long col = n0 + wc * 64 + n * 16 + cl;
        float bvv = bias[col];
#pragma unroll
        for (int m = 0; m < 8; ++m) {
            long row = m0 + wr * 128 + m * 16 + kh * 4;
#pragma unroll
            for (int r = 0; r < 4; ++r)
                out[(row + r) * (long)D_OUT + col] = acc[m][n][r] + bvv;
        }
    }
}

// ---------------------------------------------------------------------------
extern "C" void kernel_launch(void* const* d_in, const int* in_sizes, int n_in,
                              void* d_out, int out_size, void* d_ws, size_t ws_size,
                              hipStream_t stream) {
    const float* x  = (const float*)d_in[0];
    const float* bw = (const float*)d_in[1];
    const float* bb = (const float*)d_in[2];
    const float* lA = (const float*)d_in[3];
    const float* lB = (const float*)d_in[4];
    const float* rw = (const float*)d_in[5];
    const float* sc = (const float*)d_in[6];
    float* out = (float*)d_out;

    char* ws = (char*)d_ws;
    u16* Xaug  = (u16*)ws;                      // 8192*4224*2 = 69,206,016 B
    u16* Waug  = (u16*)(ws + 69206016);         // 4096*4224*2 = 34,603,008 B
    u16* A16   = (u16*)(ws + 103809024);        // 128*4096*2  =  1,048,576 B
    float* gates = (float*)(ws + 104857600);    // 8192*8*4    =    262,144 B

    convert_kernel<<<25088, 256, 0, stream>>>(x, bw, lA, lB, Xaug, Waug, A16);
    router_kernel<<<2048, 256, 0, stream>>>(x, rw, sc, gates);
    lora_h_kernel<<<256, 256, 0, stream>>>(Xaug, A16, gates);
    main_gemm<<<512, 512, 0, stream>>>(Xaug, Waug, bb, out);
}